// Round 10
// baseline (423.814 us; speedup 1.0000x reference)
//
#include <hip/hip_runtime.h>
#include <hip/hip_bf16.h>

// CRF-as-RNN mean-field on MI355X. B=2, L=21, C=3, H=W=96, N=9216, NITERS=5.
//
// w[n][m] = exp2(gs[m] + f_n . fs[m]); per iter P[n][l] = sum_m w[n][m]*MQ[l][m]
// via bf16 MFMA 16x16x32. R9 diagnosis: every round since R3 was GRID-
// STARVED — the m-split S was workspace-limited (Ppart = S x 1.62MB), giving
// 2.25-4.5 blocks/CU when 8 fit. THIS ROUND: atomic accumulation into ONE
// Ppart buffer (memset per iter) decouples S from workspace -> S=8, 2304
// blocks, 9/CU, full 8-block residency. k_accum keeps the best pieces:
// R7 64-row structure, M stride-72 staging with const rows 21..31 (row 21
// = 1.0 -> MFMA col 21 = rowsum(W) free, branch-free), R8's PROVEN zero-
// conflict W 64x64 16B-chunk XOR swizzle, thin lgkm-only barriers (no
// vmcnt drain), depth-1 prefetch. msg = P/P[21]; Q = softmax_l(-(E0+msg));
// MQ = Mu@Q (bf16).

#define BB 2
#define LL 21
#define LP (LL + 1)   // Ppart rows: 21 msg cols + 1 rowsum col
#define NNPX 9216
#define NITERS 5
#define MSPLIT 8      // m-split (atomic accumulation; not workspace-bound)
#define LOG2E 1.4426950408889634f

// raw barrier: waits LDS ops of this wave, syncs, does NOT drain vmcnt
#define BARRIER() asm volatile("s_waitcnt lgkmcnt(0)\n\ts_barrier" ::: "memory")

typedef __attribute__((ext_vector_type(8))) short short8;
typedef __attribute__((ext_vector_type(4))) float f32x4;

static __device__ inline unsigned int pk_bf16(float a, float b) {
    __hip_bfloat162 h = __float22bfloat162_rn(make_float2(a, b));
    unsigned int u;
    __builtin_memcpy(&u, &h, 4);
    return u;
}

// ---------------- prep: features + Q0 + MQ0(bf16) ----------------
__global__ __launch_bounds__(256) void k_prep(
        const float* __restrict__ E0, const float* __restrict__ Refs,
        const float* __restrict__ Mu,
        float4* __restrict__ FN, float4* __restrict__ FS,
        __hip_bfloat16* __restrict__ MQ) {
    __shared__ float muS[LL * LL];
    for (int i = threadIdx.x; i < LL * LL; i += 256) muS[i] = Mu[i];
    __syncthreads();

    int idx = blockIdx.x * 256 + threadIdx.x;      // b*N + n
    int b = idx / NNPX, n = idx % NNPX;

    const float* rb = Refs + (size_t)b * 3 * NNPX + n;
    float r0 = rb[0], r1 = rb[NNPX], r2 = rb[2 * NNPX];
    FN[idx] = make_float4(r0, r1, r2, 0.f);
    float g = -0.5f * (r0 * r0 + r1 * r1 + r2 * r2);
    FS[idx] = make_float4(g * LOG2E, r0 * LOG2E, r1 * LOG2E, r2 * LOG2E);

    const float* eb = E0 + (size_t)b * LL * NNPX + n;
    float x[LL];
    float mx = -1e30f;
    for (int l = 0; l < LL; ++l) { x[l] = -eb[(size_t)l * NNPX]; mx = fmaxf(mx, x[l]); }
    float s = 0.f;
    for (int l = 0; l < LL; ++l) { x[l] = __builtin_amdgcn_exp2f((x[l] - mx) * LOG2E); s += x[l]; }
    float rs = __builtin_amdgcn_rcpf(s);
    for (int l = 0; l < LL; ++l) x[l] *= rs;

    __hip_bfloat16* mq = MQ + (size_t)b * LL * NNPX + n;
    for (int k = 0; k < LL; ++k) {
        float a = 0.f;
        for (int l = 0; l < LL; ++l) a += muS[k * LL + l] * x[l];
        mq[(size_t)k * NNPX] = __float2bfloat16(a);
    }
}

// ---------------- accumulate via MFMA (msg + rowsum fused) ----------------
// grid (288, MSPLIT): blockIdx.x = b*144 + n-tile (64 rows), blockIdx.y = s.
// Block handles CONTIGUOUS m-tiles [s*T, (s+1)*T), T = 144/MSPLIT, tiles 64.
// C-tile accumulated into global Ppart via atomicAdd (buffer zeroed/iter).
__global__ __launch_bounds__(256, 4) void k_accum(
        const float4* __restrict__ FS, const float4* __restrict__ FN,
        const unsigned int* __restrict__ MQbf, float* __restrict__ Ppart) {
    // W: 64 rows x 64 bf16 pad-free, 16B-chunk XOR-swizzled (zero-conflict,
    // R8/R9-proven). M: 32 l x 72 k bf16, rows 21..31 constant (21 = 1.0).
    // Total 12.6 KB -> residency grid-bound (9/CU), not LDS-bound.
    __shared__ __align__(16) unsigned short Wlds[64 * 64];
    __shared__ __align__(16) unsigned short Mlds[32 * 72];

    int t = threadIdx.x;
    int rb = blockIdx.x;
    int s  = blockIdx.y;
    int b  = rb / 144;
    int n0 = (rb % 144) * 64;
    int wv = t >> 6, lane = t & 63;
    int lr = lane & 15, g = lane >> 4;

    // one-time init of constant B rows: row 21 = 1.0 (rowsum), 22..31 = 0
    for (int i = t; i < 11 * 32; i += 256) {
        int r = 21 + (i >> 5), d = i & 31;
        ((unsigned int*)&Mlds[r * 72])[d] = (r == 21) ? 0x3F803F80u : 0u;
    }

    // w-gen mapping (block-wide): thread owns rows ng+16i (i<4), m-quad mq
    int mq = t & 15;
    int ng = t >> 4;
    float fnx[4], fny[4], fnz[4];
    #pragma unroll
    for (int i = 0; i < 4; ++i) {
        float4 v = FN[b * NNPX + n0 + ng + 16 * i];
        fnx[i] = v.x; fny[i] = v.y; fnz[i] = v.z;
    }

    const int T  = 144 / MSPLIT;
    const int t0 = s * T;
    const float4* fsb = FS + (size_t)b * NNPX;
    const unsigned int* mqb = MQbf + (size_t)b * LL * (NNPX / 2);

    // MQ stage ownership: dwords idx = t + 256*r (r<3), idx < 21*32 = 672
    int sl0 = t >> 5, sm0 = t & 31;
    int sl1 = (t + 256) >> 5, sm1 = (t + 256) & 31;
    int sl2 = (t + 512) >> 5, sm2 = (t + 512) & 31;   // valid iff t<160

    f32x4 acc0 = {0.f, 0.f, 0.f, 0.f};   // C cols 0..15
    f32x4 acc1 = {0.f, 0.f, 0.f, 0.f};   // C cols 16..21 (22..31 discarded)

    // W-write swizzle: logical 8B-granule (mq) of row r: physical chunk
    // (mq>>1)^(r&7), half mq&1; r&7 == ng&7 for all i.
    int wcol = (((mq >> 1) ^ (ng & 7)) << 3) + ((mq & 1) << 2);

    // A-read swizzled offsets (16B chunks g and g+4 of row wv*16+lr)
    int row = wv * 16 + lr;
    int ia0 = row * 64 + ((g ^ (lr & 7)) << 3);
    int ia1 = row * 64 + (((g + 4) ^ (lr & 7)) << 3);

    // depth-1 prefetch registers
    float4 fsA0, fsA1, fsA2, fsA3;
    unsigned int mrA0, mrA1, mrA2;

    auto LOAD = [&](int tile) {
        int m0 = (t0 + tile) * 64;
        fsA0 = fsb[m0 + 4 * mq + 0]; fsA1 = fsb[m0 + 4 * mq + 1];
        fsA2 = fsb[m0 + 4 * mq + 2]; fsA3 = fsb[m0 + 4 * mq + 3];
        int mo0 = (t0 + tile) * 32;
        mrA0 = mqb[(size_t)sl0 * (NNPX / 2) + mo0 + sm0];
        mrA1 = mqb[(size_t)sl1 * (NNPX / 2) + mo0 + sm1];
        if (t < 160) mrA2 = mqb[(size_t)sl2 * (NNPX / 2) + mo0 + sm2];
    };
    auto STORE = [&]() {
        ((unsigned int*)&Mlds[sl0 * 72])[sm0] = mrA0;
        ((unsigned int*)&Mlds[sl1 * 72])[sm1] = mrA1;
        if (t < 160) ((unsigned int*)&Mlds[sl2 * 72])[sm2] = mrA2;
        #pragma unroll
        for (int i = 0; i < 4; ++i) {
            float w0 = __builtin_amdgcn_exp2f(fsA0.x + fnx[i] * fsA0.y + fny[i] * fsA0.z + fnz[i] * fsA0.w);
            float w1 = __builtin_amdgcn_exp2f(fsA1.x + fnx[i] * fsA1.y + fny[i] * fsA1.z + fnz[i] * fsA1.w);
            float w2 = __builtin_amdgcn_exp2f(fsA2.x + fnx[i] * fsA2.y + fny[i] * fsA2.z + fnz[i] * fsA2.w);
            float w3 = __builtin_amdgcn_exp2f(fsA3.x + fnx[i] * fsA3.y + fny[i] * fsA3.z + fnz[i] * fsA3.w);
            uint2 pk;
            pk.x = pk_bf16(w0, w1);
            pk.y = pk_bf16(w2, w3);
            *(uint2*)&Wlds[(ng + 16 * i) * 64 + wcol] = pk;
        }
    };
    auto MFMA = [&]() {
        short8 a0  = *(const short8*)&Wlds[ia0];
        short8 a1  = *(const short8*)&Wlds[ia1];
        short8 b00 = *(const short8*)&Mlds[lr * 72 + g * 8];
        short8 b01 = *(const short8*)&Mlds[lr * 72 + g * 8 + 32];
        short8 b10 = *(const short8*)&Mlds[(16 + lr) * 72 + g * 8];
        short8 b11 = *(const short8*)&Mlds[(16 + lr) * 72 + g * 8 + 32];
        acc0 = __builtin_amdgcn_mfma_f32_16x16x32_bf16(a0, b00, acc0, 0, 0, 0);
        acc0 = __builtin_amdgcn_mfma_f32_16x16x32_bf16(a1, b01, acc0, 0, 0, 0);
        acc1 = __builtin_amdgcn_mfma_f32_16x16x32_bf16(a0, b10, acc1, 0, 0, 0);
        acc1 = __builtin_amdgcn_mfma_f32_16x16x32_bf16(a1, b11, acc1, 0, 0, 0);
    };

    // ---- prologue: tile 0 loads in flight ----
    LOAD(0);

    // ---- main loop: 2 thin barriers per tile; single LDS buffer safe
    // (each BARRIER's lgkmcnt(0) retires this wave's LDS ops first) ----
    for (int tt = 0; tt < T; ++tt) {
        BARRIER();                       // all waves done reading tile tt-1
        STORE();                         // stage MQ + w-gen (counted vmcnt)
        if (tt + 1 < T) LOAD(tt + 1);    // next tile's globals in flight
        BARRIER();                       // LDS writes visible
        MFMA();
    }

    // epilogue: atomic-accumulate C tile (layout col=lane&15, row=qr*4+r)
    int col = lane & 15, qr = lane >> 4;
    float* pp = Ppart + (size_t)b * LP * NNPX;
    for (int r = 0; r < 4; ++r) {
        int n = n0 + wv * 16 + qr * 4 + r;
        atomicAdd(&pp[(size_t)col * NNPX + n], acc0[r]);
        if (col < LP - 16) atomicAdd(&pp[(size_t)(16 + col) * NNPX + n], acc1[r]);
    }
}

// ---------------- softmax + Potts mix (single Ppart buffer) ----------------
template <bool LAST>
__global__ __launch_bounds__(256) void k_softmax(
        const float* __restrict__ E0, const float* __restrict__ Ppart,
        const float* __restrict__ Mu,
        __hip_bfloat16* __restrict__ MQ, float* __restrict__ Out) {
    __shared__ float muS[LL * LL];
    for (int i = threadIdx.x; i < LL * LL; i += 256) muS[i] = Mu[i];
    __syncthreads();

    int idx = blockIdx.x * 256 + threadIdx.x;
    int b = idx / NNPX, n = idx % NNPX;

    const float* pp = Ppart + (size_t)b * LP * NNPX + n;
    float rinv = __builtin_amdgcn_rcpf(pp[(size_t)LL * NNPX]);  // rowsum col

    const float* eb = E0 + (size_t)b * LL * NNPX + n;
    float P[LL];
    float mx = -1e30f;
    for (int l = 0; l < LL; ++l) {
        P[l] = -(eb[(size_t)l * NNPX] + pp[(size_t)l * NNPX] * rinv);
        mx = fmaxf(mx, P[l]);
    }
    float ssum = 0.f;
    for (int l = 0; l < LL; ++l) { P[l] = __builtin_amdgcn_exp2f((P[l] - mx) * LOG2E); ssum += P[l]; }
    float rs = __builtin_amdgcn_rcpf(ssum);
    for (int l = 0; l < LL; ++l) P[l] *= rs;

    if (LAST) {
        float* ob = Out + (size_t)b * LL * NNPX + n;
        for (int l = 0; l < LL; ++l) ob[(size_t)l * NNPX] = P[l];
    } else {
        __hip_bfloat16* mq = MQ + (size_t)b * LL * NNPX + n;
        for (int k = 0; k < LL; ++k) {
            float a = 0.f;
            for (int l = 0; l < LL; ++l) a += muS[k * LL + l] * P[l];
            mq[(size_t)k * NNPX] = __float2bfloat16(a);
        }
    }
}

extern "C" void kernel_launch(void* const* d_in, const int* in_sizes, int n_in,
                              void* d_out, int out_size, void* d_ws, size_t ws_size,
                              hipStream_t stream) {
    const float* E0   = (const float*)d_in[0];
    const float* Refs = (const float*)d_in[1];
    const float* Mu   = (const float*)d_in[2];
    float* out = (float*)d_out;

    char* w = (char*)d_ws;
    size_t off = 0;
    auto alloc = [&](size_t bytes) {
        void* p = w + off;
        off += (bytes + 255) & ~(size_t)255;
        return p;
    };
    float4* FN     = (float4*)alloc((size_t)BB * NNPX * sizeof(float4));
    float4* FS     = (float4*)alloc((size_t)BB * NNPX * sizeof(float4));
    __hip_bfloat16* MQbf = (__hip_bfloat16*)alloc((size_t)BB * LL * NNPX * sizeof(__hip_bfloat16));
    size_t psz = (size_t)BB * LP * NNPX * sizeof(float);
    float* Ppart = (float*)alloc(psz);

    k_prep<<<BB * NNPX / 256, 256, 0, stream>>>(E0, Refs, Mu, FN, FS, MQbf);
    for (int it = 0; it < NITERS; ++it) {
        hipMemsetAsync(Ppart, 0, psz, stream);
        k_accum<<<dim3(288, MSPLIT), 256, 0, stream>>>(FS, FN, (const unsigned int*)MQbf, Ppart);
        if (it == NITERS - 1)
            k_softmax<true><<<BB * NNPX / 256, 256, 0, stream>>>(E0, Ppart, Mu, MQbf, out);
        else
            k_softmax<false><<<BB * NNPX / 256, 256, 0, stream>>>(E0, Ppart, Mu, MQbf, out);
    }
}

// Round 11
// 387.326 us; speedup vs baseline: 1.0942x; 1.0942x over previous
//
#include <hip/hip_runtime.h>
#include <hip/hip_bf16.h>

// CRF-as-RNN mean-field on MI355X. B=2, L=21, C=3, H=W=96, N=9216, NITERS=5.
//
// w[n][m] = exp2(gs[m] + f_n . fs[m]); per iter P[n][l] = sum_m w[n][m]*MQ[l][m]
// via bf16 MFMA 16x16x32. Base = R7 champion (store Ppart S-partials, thin
// lgkm-only barriers, depth-1 prefetch, const B-rows -> MFMA col 21 =
// rowsum(W) free). Fixes this round, both counter-derived:
// (1) BOTH LDS tiles pad-free 64-col XOR-swizzled (chunk ^= row&7). R10
//     isolated the remaining 2.65M conflict cycles to the stride-72 M-tile
//     b128 reads (8 lanes, different rows, same 4-bank group = 8-way);
//     W swizzle alone measured ZERO conflicts in R8. Constant rows are
//     permutation-invariant so their init stays linear.
// (2) k_prep/k_softmax were thread-starved: 18432 threads = 0.28 waves/SIMD
//     (72% of CUs idle), ~13us each. Now 4 waves per 64-pixel tile: wave q
//     owns l-chunk [6q, 6q+6), LDS reduce for rowsum/max/sum, LDS-shared Q
//     for the Mu-mix; all loads stay coalesced. NO atomics (R10: +38MB HBM
//     write-through). msg = P/P[21]; Q = softmax_l(-(E0+msg)); MQ = Mu@Q.

#define BB 2
#define LL 21
#define LP (LL + 1)   // Ppart rows: 21 msg cols + 1 rowsum col
#define NNPX 9216
#define NITERS 5
#define LOG2E 1.4426950408889634f

// raw barrier: waits LDS ops of this wave, syncs, does NOT drain vmcnt
#define BARRIER() asm volatile("s_waitcnt lgkmcnt(0)\n\ts_barrier" ::: "memory")

typedef __attribute__((ext_vector_type(8))) short short8;
typedef __attribute__((ext_vector_type(4))) float f32x4;

static __device__ inline unsigned int pk_bf16(float a, float b) {
    __hip_bfloat162 h = __float22bfloat162_rn(make_float2(a, b));
    unsigned int u;
    __builtin_memcpy(&u, &h, 4);
    return u;
}

// ---------------- prep: features + Q0 + MQ0(bf16), 4 waves / 64 px ----------
__global__ __launch_bounds__(256) void k_prep(
        const float* __restrict__ E0, const float* __restrict__ Refs,
        const float* __restrict__ Mu,
        float4* __restrict__ FN, float4* __restrict__ FS,
        __hip_bfloat16* __restrict__ MQ) {
    __shared__ float muS[LL * LL];
    __shared__ float red1[4][64], red2[4][64];
    __shared__ float Qs[LL][64];

    int t = threadIdx.x;
    for (int i = t; i < LL * LL; i += 256) muS[i] = Mu[i];

    int q = t >> 6, px = t & 63;
    int pid = blockIdx.x * 64 + px;          // b*N + n (64-tiles never cross b)
    int b = pid / NNPX, n = pid % NNPX;

    if (q == 0) {  // features: one lane per pixel, coalesced
        const float* rb = Refs + (size_t)b * 3 * NNPX + n;
        float r0 = rb[0], r1 = rb[NNPX], r2 = rb[2 * NNPX];
        FN[pid] = make_float4(r0, r1, r2, 0.f);
        float g = -0.5f * (r0 * r0 + r1 * r1 + r2 * r2);
        FS[pid] = make_float4(g * LOG2E, r0 * LOG2E, r1 * LOG2E, r2 * LOG2E);
    }

    int l0 = q * 6;
    const float* eb = E0 + (size_t)b * LL * NNPX + n;
    float x[6];
    float mx = -1e30f;
    #pragma unroll
    for (int i = 0; i < 6; ++i) {
        int l = l0 + i;
        x[i] = (l < LL) ? -eb[(size_t)l * NNPX] : -1e30f;
        mx = fmaxf(mx, x[i]);
    }
    red1[q][px] = mx;
    __syncthreads();
    mx = fmaxf(fmaxf(red1[0][px], red1[1][px]), fmaxf(red1[2][px], red1[3][px]));
    float s = 0.f;
    #pragma unroll
    for (int i = 0; i < 6; ++i) { x[i] = __builtin_amdgcn_exp2f((x[i] - mx) * LOG2E); s += x[i]; }
    red2[q][px] = s;
    __syncthreads();
    float rs = __builtin_amdgcn_rcpf(red2[0][px] + red2[1][px] + red2[2][px] + red2[3][px]);
    #pragma unroll
    for (int i = 0; i < 6; ++i) if (l0 + i < LL) Qs[l0 + i][px] = x[i] * rs;
    __syncthreads();

    __hip_bfloat16* mq = MQ + (size_t)b * LL * NNPX + n;
    #pragma unroll
    for (int j = 0; j < 6; ++j) {
        int k = l0 + j;
        if (k < LL) {
            float a = 0.f;
            for (int l = 0; l < LL; ++l) a += muS[k * LL + l] * Qs[l][px];
            mq[(size_t)k * NNPX] = __float2bfloat16(a);
        }
    }
}

// ---------------- accumulate via MFMA (msg + rowsum fused) ----------------
// grid (288, S): blockIdx.x = b*144 + n-tile (64 rows), blockIdx.y = s.
// Block handles CONTIGUOUS m-tiles [s*T, (s+1)*T), T = 144/S, tiles of 64.
__global__ __launch_bounds__(256, 4) void k_accum(
        const float4* __restrict__ FS, const float4* __restrict__ FN,
        const unsigned int* __restrict__ MQbf, float* __restrict__ Ppart, int S) {
    // W: 64 x 64 bf16 pad-free, 16B-chunk XOR swizzle (R8-proven 0-conflict).
    // M: 32 x 64 bf16 pad-free, same swizzle (rows 21..31 constant; constant
    // rows are permutation-invariant so init is linear). Total 12.3 KB.
    __shared__ __align__(16) unsigned short Wlds[64 * 64];
    __shared__ __align__(16) unsigned short Mlds[32 * 64];

    int t = threadIdx.x;
    int rb = blockIdx.x;
    int s  = blockIdx.y;
    int b  = rb / 144;
    int n0 = (rb % 144) * 64;
    int wv = t >> 6, lane = t & 63;
    int lr = lane & 15, g = lane >> 4;

    // one-time init of constant B rows: row 21 = 1.0 (rowsum), 22..31 = 0
    for (int i = t; i < 11 * 32; i += 256) {
        int r = 21 + (i >> 5), d = i & 31;
        ((unsigned int*)&Mlds[r * 64])[d] = (r == 21) ? 0x3F803F80u : 0u;
    }

    // w-gen mapping (block-wide): thread owns rows ng+16i (i<4), m-quad mq
    int mq = t & 15;
    int ng = t >> 4;
    float fnx[4], fny[4], fnz[4];
    #pragma unroll
    for (int i = 0; i < 4; ++i) {
        float4 v = FN[b * NNPX + n0 + ng + 16 * i];
        fnx[i] = v.x; fny[i] = v.y; fnz[i] = v.z;
    }

    const int T  = 144 / S;
    const int t0 = s * T;
    const float4* fsb = FS + (size_t)b * NNPX;
    const unsigned int* mqb = MQbf + (size_t)b * LL * (NNPX / 2);

    // MQ stage ownership: dwords idx = t + 256*r (r<3), idx < 21*32 = 672
    int sl0 = t >> 5, sm0 = t & 31;
    int sl1 = (t + 256) >> 5, sm1 = (t + 256) & 31;
    int sl2 = (t + 512) >> 5, sm2 = (t + 512) & 31;   // valid iff t<160
    // swizzled M-write dword offsets: row*32 + ((d>>2)^(row&7))*4 + (d&3)
    int mw0 = sl0 * 32 + (((sm0 >> 2) ^ (sl0 & 7)) << 2) + (sm0 & 3);
    int mw1 = sl1 * 32 + (((sm1 >> 2) ^ (sl1 & 7)) << 2) + (sm1 & 3);
    int mw2 = sl2 * 32 + (((sm2 >> 2) ^ (sl2 & 7)) << 2) + (sm2 & 3);

    f32x4 acc0 = {0.f, 0.f, 0.f, 0.f};   // C cols 0..15
    f32x4 acc1 = {0.f, 0.f, 0.f, 0.f};   // C cols 16..21 (22..31 discarded)

    // W-write swizzle: 8B granule mq of row r -> chunk (mq>>1)^(r&7), half mq&1
    int wcol = (((mq >> 1) ^ (ng & 7)) << 3) + ((mq & 1) << 2);

    // swizzled A/B read offsets (shorts)
    int row = wv * 16 + lr;
    int ia0 = row * 64 + ((g ^ (lr & 7)) << 3);
    int ia1 = row * 64 + (((g + 4) ^ (lr & 7)) << 3);
    int ib0 = lr * 64 + ((g ^ (lr & 7)) << 3);          // M row lr
    int ib1 = lr * 64 + (((g + 4) ^ (lr & 7)) << 3);
    int ib2 = (16 + lr) * 64 + ((g ^ (lr & 7)) << 3);   // M row 16+lr (same &7)
    int ib3 = (16 + lr) * 64 + (((g + 4) ^ (lr & 7)) << 3);

    // depth-1 prefetch registers
    float4 fsA0, fsA1, fsA2, fsA3;
    unsigned int mrA0, mrA1, mrA2;

    auto LOAD = [&](int tile) {
        int m0 = (t0 + tile) * 64;
        fsA0 = fsb[m0 + 4 * mq + 0]; fsA1 = fsb[m0 + 4 * mq + 1];
        fsA2 = fsb[m0 + 4 * mq + 2]; fsA3 = fsb[m0 + 4 * mq + 3];
        int mo0 = (t0 + tile) * 32;
        mrA0 = mqb[(size_t)sl0 * (NNPX / 2) + mo0 + sm0];
        mrA1 = mqb[(size_t)sl1 * (NNPX / 2) + mo0 + sm1];
        if (t < 160) mrA2 = mqb[(size_t)sl2 * (NNPX / 2) + mo0 + sm2];
    };
    auto STORE = [&]() {
        ((unsigned int*)Mlds)[mw0] = mrA0;
        ((unsigned int*)Mlds)[mw1] = mrA1;
        if (t < 160) ((unsigned int*)Mlds)[mw2] = mrA2;
        #pragma unroll
        for (int i = 0; i < 4; ++i) {
            float w0 = __builtin_amdgcn_exp2f(fsA0.x + fnx[i] * fsA0.y + fny[i] * fsA0.z + fnz[i] * fsA0.w);
            float w1 = __builtin_amdgcn_exp2f(fsA1.x + fnx[i] * fsA1.y + fny[i] * fsA1.z + fnz[i] * fsA1.w);
            float w2 = __builtin_amdgcn_exp2f(fsA2.x + fnx[i] * fsA2.y + fny[i] * fsA2.z + fnz[i] * fsA2.w);
            float w3 = __builtin_amdgcn_exp2f(fsA3.x + fnx[i] * fsA3.y + fny[i] * fsA3.z + fnz[i] * fsA3.w);
            uint2 pk;
            pk.x = pk_bf16(w0, w1);
            pk.y = pk_bf16(w2, w3);
            *(uint2*)&Wlds[(ng + 16 * i) * 64 + wcol] = pk;
        }
    };
    auto MFMA = [&]() {
        short8 a0  = *(const short8*)&Wlds[ia0];
        short8 a1  = *(const short8*)&Wlds[ia1];
        short8 b00 = *(const short8*)&Mlds[ib0];
        short8 b01 = *(const short8*)&Mlds[ib1];
        short8 b10 = *(const short8*)&Mlds[ib2];
        short8 b11 = *(const short8*)&Mlds[ib3];
        acc0 = __builtin_amdgcn_mfma_f32_16x16x32_bf16(a0, b00, acc0, 0, 0, 0);
        acc0 = __builtin_amdgcn_mfma_f32_16x16x32_bf16(a1, b01, acc0, 0, 0, 0);
        acc1 = __builtin_amdgcn_mfma_f32_16x16x32_bf16(a0, b10, acc1, 0, 0, 0);
        acc1 = __builtin_amdgcn_mfma_f32_16x16x32_bf16(a1, b11, acc1, 0, 0, 0);
    };

    // ---- prologue: tile 0 loads in flight ----
    LOAD(0);

    // ---- main loop: 2 thin barriers per tile; single LDS buffer safe
    // (each BARRIER's lgkmcnt(0) retires this wave's LDS ops first) ----
    for (int tt = 0; tt < T; ++tt) {
        BARRIER();                       // all waves done reading tile tt-1
        STORE();                         // stage MQ + w-gen (counted vmcnt)
        if (tt + 1 < T) LOAD(tt + 1);    // next tile's globals in flight
        BARRIER();                       // LDS writes visible
        MFMA();
    }

    // epilogue: C layout col=lane&15, row=(lane>>4)*4+reg
    int col = lane & 15, qr = lane >> 4;
    float* pp = Ppart + ((size_t)(s * BB + b) * LP) * NNPX;
    for (int r = 0; r < 4; ++r) {
        int n = n0 + wv * 16 + qr * 4 + r;
        pp[(size_t)col * NNPX + n] = acc0[r];
        if (col < LP - 16) pp[(size_t)(16 + col) * NNPX + n] = acc1[r];
    }
}

// ------- reduce partials + softmax + Potts mix, 4 waves / 64 px -------
template <bool LAST>
__global__ __launch_bounds__(256) void k_softmax(
        const float* __restrict__ E0, const float* __restrict__ Ppart,
        const float* __restrict__ Mu,
        __hip_bfloat16* __restrict__ MQ, float* __restrict__ Out, int S) {
    __shared__ float muS[LL * LL];
    __shared__ float rsumS[64];
    __shared__ float red1[4][64], red2[4][64];
    __shared__ float Qs[LL][64];

    int t = threadIdx.x;
    if (!LAST) for (int i = t; i < LL * LL; i += 256) muS[i] = Mu[i];

    int q = t >> 6, px = t & 63;
    int pid = blockIdx.x * 64 + px;
    int b = pid / NNPX, n = pid % NNPX;

    int l0 = q * 6;
    const float* ppb = Ppart + n;
    const float* eb = E0 + (size_t)b * LL * NNPX + n;

    float Pa[6], e0v[6];
    #pragma unroll
    for (int i = 0; i < 6; ++i) {
        int l = l0 + i;
        Pa[i] = 0.f; e0v[i] = 0.f;
        if (l < LL) {
            for (int s = 0; s < S; ++s)
                Pa[i] += ppb[((size_t)(s * BB + b) * LP + l) * NNPX];
            e0v[i] = eb[(size_t)l * NNPX];
        }
    }
    if (q == 3) {
        float racc = 0.f;
        for (int s = 0; s < S; ++s)
            racc += ppb[((size_t)(s * BB + b) * LP + LL) * NNPX];
        rsumS[px] = racc;
    }
    __syncthreads();
    float rinv = __builtin_amdgcn_rcpf(rsumS[px]);

    float x[6];
    float mx = -1e30f;
    #pragma unroll
    for (int i = 0; i < 6; ++i) {
        x[i] = (l0 + i < LL) ? -(e0v[i] + Pa[i] * rinv) : -1e30f;
        mx = fmaxf(mx, x[i]);
    }
    red1[q][px] = mx;
    __syncthreads();
    mx = fmaxf(fmaxf(red1[0][px], red1[1][px]), fmaxf(red1[2][px], red1[3][px]));
    float ssum = 0.f;
    #pragma unroll
    for (int i = 0; i < 6; ++i) { x[i] = __builtin_amdgcn_exp2f((x[i] - mx) * LOG2E); ssum += x[i]; }
    red2[q][px] = ssum;
    __syncthreads();
    float rs = __builtin_amdgcn_rcpf(red2[0][px] + red2[1][px] + red2[2][px] + red2[3][px]);

    if (LAST) {
        float* ob = Out + (size_t)b * LL * NNPX + n;
        #pragma unroll
        for (int i = 0; i < 6; ++i) if (l0 + i < LL) ob[(size_t)(l0 + i) * NNPX] = x[i] * rs;
    } else {
        #pragma unroll
        for (int i = 0; i < 6; ++i) if (l0 + i < LL) Qs[l0 + i][px] = x[i] * rs;
        __syncthreads();
        __hip_bfloat16* mq = MQ + (size_t)b * LL * NNPX + n;
        #pragma unroll
        for (int j = 0; j < 6; ++j) {
            int k = l0 + j;
            if (k < LL) {
                float a = 0.f;
                for (int l = 0; l < LL; ++l) a += muS[k * LL + l] * Qs[l][px];
                mq[(size_t)k * NNPX] = __float2bfloat16(a);
            }
        }
    }
}

extern "C" void kernel_launch(void* const* d_in, const int* in_sizes, int n_in,
                              void* d_out, int out_size, void* d_ws, size_t ws_size,
                              hipStream_t stream) {
    const float* E0   = (const float*)d_in[0];
    const float* Refs = (const float*)d_in[1];
    const float* Mu   = (const float*)d_in[2];
    float* out = (float*)d_out;

    char* w = (char*)d_ws;
    size_t off = 0;
    auto alloc = [&](size_t bytes) {
        void* p = w + off;
        off += (bytes + 255) & ~(size_t)255;
        return p;
    };
    float4* FN     = (float4*)alloc((size_t)BB * NNPX * sizeof(float4));
    float4* FS     = (float4*)alloc((size_t)BB * NNPX * sizeof(float4));
    __hip_bfloat16* MQbf = (__hip_bfloat16*)alloc((size_t)BB * LL * NNPX * sizeof(__hip_bfloat16));

    // m-split S (divisor of 144, capped at 8) whose partial buffer fits in ws
    size_t per = (size_t)BB * LP * NNPX * sizeof(float);
    size_t avail = ws_size > off ? ws_size - off : 0;
    int Smax = (int)(avail / (per + 256));
    static const int divs[] = {8, 6, 4, 3, 2, 1};
    int S = 1;
    for (int i = 0; i < 6; ++i) if (divs[i] <= Smax) { S = divs[i]; break; }
    float* Ppart = (float*)alloc((size_t)S * per);

    k_prep<<<BB * NNPX / 64, 256, 0, stream>>>(E0, Refs, Mu, FN, FS, MQbf);
    for (int it = 0; it < NITERS; ++it) {
        k_accum<<<dim3(288, S), 256, 0, stream>>>(FS, FN, (const unsigned int*)MQbf, Ppart, S);
        if (it == NITERS - 1)
            k_softmax<true><<<BB * NNPX / 64, 256, 0, stream>>>(E0, Ppart, Mu, MQbf, out, S);
        else
            k_softmax<false><<<BB * NNPX / 64, 256, 0, stream>>>(E0, Ppart, Mu, MQbf, out, S);
    }
}

// Round 12
// 372.556 us; speedup vs baseline: 1.1376x; 1.0396x over previous
//
#include <hip/hip_runtime.h>
#include <hip/hip_bf16.h>

// CRF-as-RNN mean-field on MI355X. B=2, L=21, C=3, H=W=96, N=9216, NITERS=5.
//
// w[n][m] = exp2(gs[m] + f_n . fs[m]); per iter P[n][l] = sum_m w[n][m]*MQ[l][m]
// via bf16 MFMA 16x16x32. R11 accounting: per-tile wall ~963cy vs ~300cy of
// pipe work, all pipes <=30% busy — the W-LDS round-trip + 2 cross-wave
// barriers per tile was the exposed serial chain. THIS ROUND: no W tile.
// Each lane generates its OWN A-fragment in registers; FS is staged to LDS
// (1KB, coalesced) and read via broadcast ds_read_b128 (16-lane groups
// share an address; XOR slot swizzle slot(m)=(m&~7)|((m^(m>>3))&7) puts the
// 4 distinct addresses of each read on 4 disjoint bank-quads:
//   a0 read j: slots 8g+(j^g), bank-quad 4(j^g), g=0..3 -> {j,j^1,j^2,j^3}
//   disjoint; a1 read j: slots 32+8g+((j^g)^4), same argument. conflict-free.)
// M tile keeps R11's proven zero-conflict swizzle, const rows 21..31
// (row 21 = 1.0 -> MFMA col 21 = rowsum(W) free). FS+M double-buffered
// (10KB) -> ONE thin lgkm-only barrier per tile; the whole tile body is
// intra-wave so the compiler pipelines with counted waits. k_prep/k_softmax
// = R11 (4 waves / 64 px). msg = P/P[21]; Q = softmax_l(-(E0+msg)); MQ = Mu@Q.

#define BB 2
#define LL 21
#define LP (LL + 1)   // Ppart rows: 21 msg cols + 1 rowsum col
#define NNPX 9216
#define NITERS 5
#define LOG2E 1.4426950408889634f

// raw barrier: waits LDS ops of this wave, syncs, does NOT drain vmcnt
#define BARRIER() asm volatile("s_waitcnt lgkmcnt(0)\n\ts_barrier" ::: "memory")

typedef __attribute__((ext_vector_type(8))) short short8;
typedef __attribute__((ext_vector_type(4))) float f32x4;
typedef __attribute__((ext_vector_type(4))) unsigned int u32x4;

static __device__ inline unsigned int pk_bf16(float a, float b) {
    __hip_bfloat162 h = __float22bfloat162_rn(make_float2(a, b));
    unsigned int u;
    __builtin_memcpy(&u, &h, 4);
    return u;
}

// ---------------- prep: features + Q0 + MQ0(bf16), 4 waves / 64 px ----------
__global__ __launch_bounds__(256) void k_prep(
        const float* __restrict__ E0, const float* __restrict__ Refs,
        const float* __restrict__ Mu,
        float4* __restrict__ FN, float4* __restrict__ FS,
        __hip_bfloat16* __restrict__ MQ) {
    __shared__ float muS[LL * LL];
    __shared__ float red1[4][64], red2[4][64];
    __shared__ float Qs[LL][64];

    int t = threadIdx.x;
    for (int i = t; i < LL * LL; i += 256) muS[i] = Mu[i];

    int q = t >> 6, px = t & 63;
    int pid = blockIdx.x * 64 + px;          // b*N + n (64-tiles never cross b)
    int b = pid / NNPX, n = pid % NNPX;

    if (q == 0) {  // features: one lane per pixel, coalesced
        const float* rb = Refs + (size_t)b * 3 * NNPX + n;
        float r0 = rb[0], r1 = rb[NNPX], r2 = rb[2 * NNPX];
        FN[pid] = make_float4(r0, r1, r2, 0.f);
        float g = -0.5f * (r0 * r0 + r1 * r1 + r2 * r2);
        FS[pid] = make_float4(g * LOG2E, r0 * LOG2E, r1 * LOG2E, r2 * LOG2E);
    }

    int l0 = q * 6;
    const float* eb = E0 + (size_t)b * LL * NNPX + n;
    float x[6];
    float mx = -1e30f;
    #pragma unroll
    for (int i = 0; i < 6; ++i) {
        int l = l0 + i;
        x[i] = (l < LL) ? -eb[(size_t)l * NNPX] : -1e30f;
        mx = fmaxf(mx, x[i]);
    }
    red1[q][px] = mx;
    __syncthreads();
    mx = fmaxf(fmaxf(red1[0][px], red1[1][px]), fmaxf(red1[2][px], red1[3][px]));
    float s = 0.f;
    #pragma unroll
    for (int i = 0; i < 6; ++i) { x[i] = __builtin_amdgcn_exp2f((x[i] - mx) * LOG2E); s += x[i]; }
    red2[q][px] = s;
    __syncthreads();
    float rs = __builtin_amdgcn_rcpf(red2[0][px] + red2[1][px] + red2[2][px] + red2[3][px]);
    #pragma unroll
    for (int i = 0; i < 6; ++i) if (l0 + i < LL) Qs[l0 + i][px] = x[i] * rs;
    __syncthreads();

    __hip_bfloat16* mq = MQ + (size_t)b * LL * NNPX + n;
    #pragma unroll
    for (int j = 0; j < 6; ++j) {
        int k = l0 + j;
        if (k < LL) {
            float a = 0.f;
            for (int l = 0; l < LL; ++l) a += muS[k * LL + l] * Qs[l][px];
            mq[(size_t)k * NNPX] = __float2bfloat16(a);
        }
    }
}

// ---------------- accumulate via MFMA (msg + rowsum fused) ----------------
// grid (288, S): blockIdx.x = b*144 + n-tile (64 rows), blockIdx.y = s.
// Block handles CONTIGUOUS m-tiles [s*T, (s+1)*T), T = 144/S, tiles of 64.
__global__ __launch_bounds__(256, 4) void k_accum(
        const float4* __restrict__ FS, const float4* __restrict__ FN,
        const unsigned int* __restrict__ MQbf, float* __restrict__ Ppart, int S) {
    // FS: 2 x 64 float4 (slot-swizzled, 1KB each). M: 2 x 32x64 bf16
    // (XOR-swizzled, rows 21..31 const). Total 10KB. No W tile.
    __shared__ __align__(16) float FSlds[2][256];
    __shared__ __align__(16) unsigned short Mlds[2][32 * 64];

    int t = threadIdx.x;
    int rb = blockIdx.x;
    int s  = blockIdx.y;
    int b  = rb / 144;
    int n0 = (rb % 144) * 64;
    int wv = t >> 6, lane = t & 63;
    int lr = lane & 15, g = lane >> 4;

    // one-time init of constant B rows in BOTH buffers
    for (int i = t; i < 11 * 32 * 2; i += 256) {
        int bufi = i >= 11 * 32;
        int ii = i - bufi * 11 * 32;
        int r = 21 + (ii >> 5), d = ii & 31;
        ((unsigned int*)&Mlds[bufi][r * 64])[d] = (r == 21) ? 0x3F803F80u : 0u;
    }

    // this thread's A-row feature (row = wv*16 + lr)
    int row = wv * 16 + lr;
    float4 fv = FN[b * NNPX + n0 + row];
    float fnx = fv.x, fny = fv.y, fnz = fv.z;

    const int T  = 144 / S;
    const int t0 = s * T;
    const float* fs32 = (const float*)(FS + (size_t)b * NNPX);
    const unsigned int* mqb = MQbf + (size_t)b * LL * (NNPX / 2);

    // FS stage: thread t loads global dword (m0*4 + t) -> swizzled LDS dword
    int mloc = t >> 2, comp = t & 3;
    int fslot = (mloc & ~7) | ((mloc ^ (mloc >> 3)) & 7);
    int fsw = fslot * 4 + comp;

    // MQ stage ownership (3 dwords) + R11-proven swizzled dests
    int sl0 = t >> 5, sm0 = t & 31;
    int sl1 = (t + 256) >> 5, sm1 = (t + 256) & 31;
    int sl2 = (t + 512) >> 5, sm2 = (t + 512) & 31;   // valid iff t<160
    int mw0 = sl0 * 32 + (((sm0 >> 2) ^ (sl0 & 7)) << 2) + (sm0 & 3);
    int mw1 = sl1 * 32 + (((sm1 >> 2) ^ (sl1 & 7)) << 2) + (sm1 & 3);
    int mw2 = sl2 * 32 + (((sm2 >> 2) ^ (sl2 & 7)) << 2) + (sm2 & 3);

    // B-frag read offsets (R11-proven zero-conflict)
    int ib0 = lr * 64 + ((g ^ (lr & 7)) << 3);
    int ib1 = lr * 64 + (((g + 4) ^ (lr & 7)) << 3);
    int ib2 = (16 + lr) * 64 + ((g ^ (lr & 7)) << 3);
    int ib3 = (16 + lr) * 64 + (((g + 4) ^ (lr & 7)) << 3);

    f32x4 acc0 = {0.f, 0.f, 0.f, 0.f};   // C cols 0..15
    f32x4 acc1 = {0.f, 0.f, 0.f, 0.f};   // C cols 16..21 (22..31 discarded)

    int g8 = g * 8;

    // depth-1 prefetch registers
    float fsr;
    unsigned int mrA0, mrA1, mrA2;

    auto LOAD = [&](int tile) {
        int m0 = (t0 + tile) * 64;
        fsr = fs32[m0 * 4 + t];                        // coalesced 1 dword
        int mo0 = (t0 + tile) * 32;
        mrA0 = mqb[(size_t)sl0 * (NNPX / 2) + mo0 + sm0];
        mrA1 = mqb[(size_t)sl1 * (NNPX / 2) + mo0 + sm1];
        if (t < 160) mrA2 = mqb[(size_t)sl2 * (NNPX / 2) + mo0 + sm2];
    };
    auto STORE = [&](int buf) {
        FSlds[buf][fsw] = fsr;
        ((unsigned int*)Mlds[buf])[mw0] = mrA0;
        ((unsigned int*)Mlds[buf])[mw1] = mrA1;
        if (t < 160) ((unsigned int*)Mlds[buf])[mw2] = mrA2;
    };
    auto COMPUTE = [&](int buf) {
        const float4* FB = (const float4*)FSlds[buf];
        // A-fragment half 0: k-slots m = 8g + j  (swizzled slot 8g + (j^g))
        float w[8];
        #pragma unroll
        for (int j = 0; j < 8; ++j) {
            float4 F = FB[g8 + (j ^ g)];
            w[j] = __builtin_amdgcn_exp2f(F.x + fnx * F.y + fny * F.z + fnz * F.w);
        }
        u32x4 ap;
        #pragma unroll
        for (int j = 0; j < 4; ++j) ap[j] = pk_bf16(w[2 * j], w[2 * j + 1]);
        short8 a0 = __builtin_bit_cast(short8, ap);
        // A-fragment half 1: m = 32 + 8g + j  (slot 32 + 8g + ((j^g)^4))
        #pragma unroll
        for (int j = 0; j < 8; ++j) {
            float4 F = FB[32 + g8 + ((j ^ g) ^ 4)];
            w[j] = __builtin_amdgcn_exp2f(F.x + fnx * F.y + fny * F.z + fnz * F.w);
        }
        #pragma unroll
        for (int j = 0; j < 4; ++j) ap[j] = pk_bf16(w[2 * j], w[2 * j + 1]);
        short8 a1 = __builtin_bit_cast(short8, ap);

        short8 b00 = *(const short8*)&Mlds[buf][ib0];
        short8 b01 = *(const short8*)&Mlds[buf][ib1];
        short8 b10 = *(const short8*)&Mlds[buf][ib2];
        short8 b11 = *(const short8*)&Mlds[buf][ib3];
        acc0 = __builtin_amdgcn_mfma_f32_16x16x32_bf16(a0, b00, acc0, 0, 0, 0);
        acc0 = __builtin_amdgcn_mfma_f32_16x16x32_bf16(a1, b01, acc0, 0, 0, 0);
        acc1 = __builtin_amdgcn_mfma_f32_16x16x32_bf16(a0, b10, acc1, 0, 0, 0);
        acc1 = __builtin_amdgcn_mfma_f32_16x16x32_bf16(a1, b11, acc1, 0, 0, 0);
    };

    // ---- prologue: stage tile 0 into buf 0 ----
    LOAD(0);
    STORE(0);
    BARRIER();

    // ---- main loop: ONE thin barrier per tile. Safety: stage(t+1) writes
    // buf^1, whose last readers (compute(t-1)) all finished before the
    // barrier at the end of iteration t-1 (program order + barrier). ----
    for (int tt = 0; tt < T; ++tt) {
        int cur = tt & 1;
        if (tt + 1 < T) LOAD(tt + 1);    // globals in flight across compute
        COMPUTE(cur);
        if (tt + 1 < T) STORE(cur ^ 1);
        BARRIER();
    }

    // epilogue: C layout col=lane&15, row=(lane>>4)*4+reg
    int col = lane & 15, qr = lane >> 4;
    float* pp = Ppart + ((size_t)(s * BB + b) * LP) * NNPX;
    for (int r = 0; r < 4; ++r) {
        int n = n0 + wv * 16 + qr * 4 + r;
        pp[(size_t)col * NNPX + n] = acc0[r];
        if (col < LP - 16) pp[(size_t)(16 + col) * NNPX + n] = acc1[r];
    }
}

// ------- reduce partials + softmax + Potts mix, 4 waves / 64 px -------
template <bool LAST>
__global__ __launch_bounds__(256) void k_softmax(
        const float* __restrict__ E0, const float* __restrict__ Ppart,
        const float* __restrict__ Mu,
        __hip_bfloat16* __restrict__ MQ, float* __restrict__ Out, int S) {
    __shared__ float muS[LL * LL];
    __shared__ float rsumS[64];
    __shared__ float red1[4][64], red2[4][64];
    __shared__ float Qs[LL][64];

    int t = threadIdx.x;
    if (!LAST) for (int i = t; i < LL * LL; i += 256) muS[i] = Mu[i];

    int q = t >> 6, px = t & 63;
    int pid = blockIdx.x * 64 + px;
    int b = pid / NNPX, n = pid % NNPX;

    int l0 = q * 6;
    const float* ppb = Ppart + n;
    const float* eb = E0 + (size_t)b * LL * NNPX + n;

    float Pa[6], e0v[6];
    #pragma unroll
    for (int i = 0; i < 6; ++i) {
        int l = l0 + i;
        Pa[i] = 0.f; e0v[i] = 0.f;
        if (l < LL) {
            for (int s = 0; s < S; ++s)
                Pa[i] += ppb[((size_t)(s * BB + b) * LP + l) * NNPX];
            e0v[i] = eb[(size_t)l * NNPX];
        }
    }
    if (q == 3) {
        float racc = 0.f;
        for (int s = 0; s < S; ++s)
            racc += ppb[((size_t)(s * BB + b) * LP + LL) * NNPX];
        rsumS[px] = racc;
    }
    __syncthreads();
    float rinv = __builtin_amdgcn_rcpf(rsumS[px]);

    float x[6];
    float mx = -1e30f;
    #pragma unroll
    for (int i = 0; i < 6; ++i) {
        x[i] = (l0 + i < LL) ? -(e0v[i] + Pa[i] * rinv) : -1e30f;
        mx = fmaxf(mx, x[i]);
    }
    red1[q][px] = mx;
    __syncthreads();
    mx = fmaxf(fmaxf(red1[0][px], red1[1][px]), fmaxf(red1[2][px], red1[3][px]));
    float ssum = 0.f;
    #pragma unroll
    for (int i = 0; i < 6; ++i) { x[i] = __builtin_amdgcn_exp2f((x[i] - mx) * LOG2E); ssum += x[i]; }
    red2[q][px] = ssum;
    __syncthreads();
    float rs = __builtin_amdgcn_rcpf(red2[0][px] + red2[1][px] + red2[2][px] + red2[3][px]);

    if (LAST) {
        float* ob = Out + (size_t)b * LL * NNPX + n;
        #pragma unroll
        for (int i = 0; i < 6; ++i) if (l0 + i < LL) ob[(size_t)(l0 + i) * NNPX] = x[i] * rs;
    } else {
        #pragma unroll
        for (int i = 0; i < 6; ++i) if (l0 + i < LL) Qs[l0 + i][px] = x[i] * rs;
        __syncthreads();
        __hip_bfloat16* mq = MQ + (size_t)b * LL * NNPX + n;
        #pragma unroll
        for (int j = 0; j < 6; ++j) {
            int k = l0 + j;
            if (k < LL) {
                float a = 0.f;
                for (int l = 0; l < LL; ++l) a += muS[k * LL + l] * Qs[l][px];
                mq[(size_t)k * NNPX] = __float2bfloat16(a);
            }
        }
    }
}

extern "C" void kernel_launch(void* const* d_in, const int* in_sizes, int n_in,
                              void* d_out, int out_size, void* d_ws, size_t ws_size,
                              hipStream_t stream) {
    const float* E0   = (const float*)d_in[0];
    const float* Refs = (const float*)d_in[1];
    const float* Mu   = (const float*)d_in[2];
    float* out = (float*)d_out;

    char* w = (char*)d_ws;
    size_t off = 0;
    auto alloc = [&](size_t bytes) {
        void* p = w + off;
        off += (bytes + 255) & ~(size_t)255;
        return p;
    };
    float4* FN     = (float4*)alloc((size_t)BB * NNPX * sizeof(float4));
    float4* FS     = (float4*)alloc((size_t)BB * NNPX * sizeof(float4));
    __hip_bfloat16* MQbf = (__hip_bfloat16*)alloc((size_t)BB * LL * NNPX * sizeof(__hip_bfloat16));

    // m-split S (divisor of 144, capped at 8) whose partial buffer fits in ws
    size_t per = (size_t)BB * LP * NNPX * sizeof(float);
    size_t avail = ws_size > off ? ws_size - off : 0;
    int Smax = (int)(avail / (per + 256));
    static const int divs[] = {8, 6, 4, 3, 2, 1};
    int S = 1;
    for (int i = 0; i < 6; ++i) if (divs[i] <= Smax) { S = divs[i]; break; }
    float* Ppart = (float*)alloc((size_t)S * per);

    k_prep<<<BB * NNPX / 64, 256, 0, stream>>>(E0, Refs, Mu, FN, FS, MQbf);
    for (int it = 0; it < NITERS; ++it) {
        k_accum<<<dim3(288, S), 256, 0, stream>>>(FS, FN, (const unsigned int*)MQbf, Ppart, S);
        if (it == NITERS - 1)
            k_softmax<true><<<BB * NNPX / 64, 256, 0, stream>>>(E0, Ppart, Mu, MQbf, out, S);
        else
            k_softmax<false><<<BB * NNPX / 64, 256, 0, stream>>>(E0, Ppart, Mu, MQbf, out, S);
    }
}